// Round 4
// baseline (236.407 us; speedup 1.0000x reference)
//
#include <hip/hip_runtime.h>
#include <stdint.h>

// B=8, Lt=64, Lv=16384, D=256. Inputs fp32 (runtime-sniffed; R4-proven), out per flag.
#define NB 8
#define LT 64
#define LV 16384
#define DD 256
#define EPSV 1e-6f
#define BF16MAX 3.3895313892515355e38f

typedef unsigned short u16t;
typedef __attribute__((ext_vector_type(8))) short short8;
typedef __attribute__((ext_vector_type(4))) float floatx4;

__device__ __forceinline__ float bf2f(u16t h) {
    union { uint32_t u; float f; } cv; cv.u = ((uint32_t)h) << 16; return cv.f;
}
__device__ __forceinline__ uint32_t asu(float f) { union { float f; uint32_t u; } c; c.f = f; return c.u; }
__device__ __forceinline__ float asf(uint32_t u) { union { uint32_t u; float f; } c; c.u = u; return c.f; }
__device__ __forceinline__ u16t f2bf(float f) {
    uint32_t u = asu(f);
    return (u16t)((u + 0x7fffu + ((u >> 16) & 1u)) >> 16);  // RNE, finite
}
__device__ __forceinline__ float fixnum(float f) {
    if (f != f) return 0.0f;
    if (f > BF16MAX) return BF16MAX;    // clamp so RNE-to-bf16 can't hit inf
    if (f < -BF16MAX) return -BF16MAX;
    return f;
}
__device__ __forceinline__ float load_in(const void* p, long i, int isf32) {
    return isf32 ? ((const float*)p)[i] : bf2f(((const u16t*)p)[i]);
}
// RNE bf16 head; returns bits, sets float value. Residual a - hf is exact (Sterbenz).
__device__ __forceinline__ uint32_t bfhead(float a, float& hf) {
    uint32_t u = asu(a);
    uint32_t h = (u + 0x7fffu + ((u >> 16) & 1u)) >> 16;
    hf = asf(h << 16);
    return h;
}

// Dtype sniff over v[0..1023] by one wave (lanes 0..63). Deterministic; recomputed
// redundantly per block (2 KB L2/L3-resident read).
__device__ __forceinline__ int sniff_wave(const u16t* v, int lane) {
    int sane = 0;
    for (int i = 0; i < 16; ++i) {
        u16t h = v[lane * 16 + i];
        int ex = (h >> 7) & 0xFF;
        if ((h & 0x7FFF) == 0 || (ex >= 96 && ex < 160)) ++sane;
    }
    #pragma unroll
    for (int o = 1; o < 64; o <<= 1) sane += __shfl_xor(sane, o, 64);
    return (sane < 900) ? 1 : 0;  // 1 = fp32
}

// tnB[b][t][k] = bf16( l2norm(nan_to_num(t_row)) * 0.5 ), row-major (k contiguous).
// Fused: inline sniff + Z/S1/S2 zero + mnmxU init (blocks 0..6).
__global__ __launch_bounds__(256) void k1_tnorm(const void* t, const void* v,
                                                u16t* tnB, float* Z) {
    __shared__ float red[256];
    __shared__ int sflag;
    int row = blockIdx.x;                 // b*64 + r
    int k = threadIdx.x;
    if (k < 64) { int f = sniff_wave((const u16t*)v, k); if (k == 0) sflag = f; }
    __syncthreads();
    int isf32 = sflag;
    float x = fixnum(load_in(t, (long)row * DD + k, isf32));
    red[k] = x * x;
    __syncthreads();
    for (int s = 128; s > 0; s >>= 1) {
        if (k < s) red[k] += red[k + s];
        __syncthreads();
    }
    float scale = 0.5f / fmaxf(sqrtf(red[0]), EPSV);
    tnB[row * DD + k] = f2bf(x * scale);

    if (blockIdx.x < 7) {                 // folded zero/init
        int i = blockIdx.x * 256 + k;
        if (i < 1536) Z[i] = 0.0f;
        else if (i < 1552) {
            unsigned* u = (unsigned*)(Z + 2048);
            int j = i - 1536;
            u[j] = (j & 1) ? 0u : 0x7F7FFFFFu;  // even=min-init(+FLT_MAX), odd=max-init(0)
        }
    }
}

// MFMA GEMM + fused epilogue. Per wave: 32 v-rows x 64 t, K=256.
// A = v as 2-term RNE bf16 split (h1+h2, ~2^-18 rel; B-side bf16 quant 2^-9 dominates),
// B = tn bf16 staged in LDS. v loads are SOFTWARE-PIPELINED: kc+1's 4 loads issue
// before kc's split/MFMA work (latency hiding; values and op order bit-identical).
// MODE 0: Z[t]=sum e, S1[t]=sum exp(A/2), S2[t]=sum exp(A/2)*A; E[row][t]=e if E!=null.
// MODE 1: scores[row] = sum_t e*c[t] (+ block min/max atomics).  (fallback path)
template<int MODE>
__global__ __launch_bounds__(256) void k_gemmT(const void* v, const u16t* tnB,
                                               float* Z, float* S1, float* S2,
                                               float* EoS, const float* c,
                                               unsigned* mnmxU) {
    __shared__ u16t ldsT[64 * 264];        // [t][k], +8 pad per row (33 KB)
    __shared__ float zlds[3][4][64];       // block reduction (3 KB)
    __shared__ int sflag;
    int tid = threadIdx.x, wave = tid >> 6, lane = tid & 63;
    int c16 = lane & 15, q = lane >> 4;
    int b = blockIdx.y, tile = blockIdx.x;
    int rowbase = tile * 128 + wave * 32;  // within b

    if (tid < 64) { int f = sniff_wave((const u16t*)v, tid); if (tid == 0) sflag = f; }
    {   // stage tn[b] into LDS (64 x 256 u16, padded rows)
        const u16t* src = tnB + (size_t)b * (LT * DD);
        for (int i = tid; i < 2048; i += 256) {
            int tt = i >> 5, k8 = i & 31;
            *(uint4*)&ldsT[tt * 264 + k8 * 8] = *(const uint4*)&src[tt * DD + k8 * 8];
        }
    }
    __syncthreads();
    int isf32 = sflag;

    floatx4 acc[2][4];                     // [mt][nt]
    #pragma unroll
    for (int mt = 0; mt < 2; ++mt)
        #pragma unroll
        for (int nt = 0; nt < 4; ++nt) acc[mt][nt] = (floatx4){0.f, 0.f, 0.f, 0.f};
    float ssqp[2] = {0.f, 0.f};

    // Per-mt processing tail: identical ops/order to the unpipelined version.
    #define PROC_F8(mt)                                                        \
        do {                                                                   \
            _Pragma("unroll")                                                  \
            for (int i = 0; i < 8; ++i) f[i] = fixnum(f[i]);                   \
            union { short8 s; uint32_t u[4]; } a1, a2;                         \
            _Pragma("unroll")                                                  \
            for (int i = 0; i < 4; ++i) {                                      \
                float e0 = f[2*i], e1 = f[2*i+1];                              \
                ssqp[mt] += e0 * e0 + e1 * e1;                                 \
                float h10f, h11f, d0, d1;                                      \
                uint32_t h10 = bfhead(e0, h10f), h11 = bfhead(e1, h11f);       \
                float r10 = e0 - h10f,  r11 = e1 - h11f;                       \
                uint32_t h20 = bfhead(r10, d0), h21 = bfhead(r11, d1);         \
                a1.u[i] = h10 | (h11 << 16);                                   \
                a2.u[i] = h20 | (h21 << 16);                                   \
            }                                                                  \
            _Pragma("unroll")                                                  \
            for (int nt = 0; nt < 4; ++nt) {                                   \
                acc[mt][nt] = __builtin_amdgcn_mfma_f32_16x16x32_bf16(         \
                    a1.s, bf[nt], acc[mt][nt], 0, 0, 0);                       \
                acc[mt][nt] = __builtin_amdgcn_mfma_f32_16x16x32_bf16(         \
                    a2.s, bf[nt], acc[mt][nt], 0, 0, 0);                       \
            }                                                                  \
        } while (0)

    if (isf32) {
        const float4* vr0 = (const float4*)((const float*)v +
            ((size_t)b * LV + rowbase + c16) * DD) + q * 2;
        const float4* vr1 = (const float4*)((const float*)v +
            ((size_t)b * LV + rowbase + 16 + c16) * DD) + q * 2;
        float4 nA0 = vr0[0], nA1 = vr0[1], nB0 = vr1[0], nB1 = vr1[1];
        for (int kc = 0; kc < 8; ++kc) {
            short8 bf[4];
            #pragma unroll
            for (int nt = 0; nt < 4; ++nt)
                bf[nt] = *(const short8*)&ldsT[(nt * 16 + c16) * 264 + kc * 32 + q * 8];
            float4 cA0 = nA0, cA1 = nA1, cB0 = nB0, cB1 = nB1;
            if (kc < 7) {                 // prefetch kc+1 (issue before compute)
                int o = (kc + 1) * 8;
                nA0 = vr0[o]; nA1 = vr0[o + 1];
                nB0 = vr1[o]; nB1 = vr1[o + 1];
            }
            {
                float f[8] = {cA0.x, cA0.y, cA0.z, cA0.w, cA1.x, cA1.y, cA1.z, cA1.w};
                PROC_F8(0);
            }
            {
                float f[8] = {cB0.x, cB0.y, cB0.z, cB0.w, cB1.x, cB1.y, cB1.z, cB1.w};
                PROC_F8(1);
            }
        }
    } else {
        const uint4* vr0 = (const uint4*)((const u16t*)v +
            ((size_t)b * LV + rowbase + c16) * DD) + q;
        const uint4* vr1 = (const uint4*)((const u16t*)v +
            ((size_t)b * LV + rowbase + 16 + c16) * DD) + q;
        uint4 nA = vr0[0], nB = vr1[0];
        for (int kc = 0; kc < 8; ++kc) {
            short8 bf[4];
            #pragma unroll
            for (int nt = 0; nt < 4; ++nt)
                bf[nt] = *(const short8*)&ldsT[(nt * 16 + c16) * 264 + kc * 32 + q * 8];
            uint4 cA = nA, cB = nB;
            if (kc < 7) {                 // prefetch kc+1
                int o = (kc + 1) * 4;
                nA = vr0[o]; nB = vr1[o];
            }
            {
                float f[8] = {bf2f((u16t)cA.x), bf2f((u16t)(cA.x >> 16)),
                              bf2f((u16t)cA.y), bf2f((u16t)(cA.y >> 16)),
                              bf2f((u16t)cA.z), bf2f((u16t)(cA.z >> 16)),
                              bf2f((u16t)cA.w), bf2f((u16t)(cA.w >> 16))};
                PROC_F8(0);
            }
            {
                float f[8] = {bf2f((u16t)cB.x), bf2f((u16t)(cB.x >> 16)),
                              bf2f((u16t)cB.y), bf2f((u16t)(cB.y >> 16)),
                              bf2f((u16t)cB.z), bf2f((u16t)(cB.z >> 16)),
                              bf2f((u16t)cB.w), bf2f((u16t)(cB.w >> 16))};
                PROC_F8(1);
            }
        }
    }
    #undef PROC_F8

    // full ||v||^2 per row (row = rowbase + mt*16 + c16 at this lane)
    float ssqf[2];
    #pragma unroll
    for (int mt = 0; mt < 2; ++mt) {
        float s = ssqp[mt];
        s += __shfl_xor(s, 16, 64);
        s += __shfl_xor(s, 32, 64);
        ssqf[mt] = s;
    }
    // fac for this lane's D rows: D row = q*4+reg -> source lane q*4+reg (c16=row)
    float facr[2][4];
    #pragma unroll
    for (int mt = 0; mt < 2; ++mt)
        #pragma unroll
        for (int reg = 0; reg < 4; ++reg) {
            float ss = __shfl(ssqf[mt], q * 4 + reg, 64);
            facr[mt][reg] = 1.0f / fmaxf(sqrtf(ss), EPSV);
        }

    if (MODE == 0) {
        float zacc[4] = {0,0,0,0}, s1acc[4] = {0,0,0,0}, s2acc[4] = {0,0,0,0};
        #pragma unroll
        for (int mt = 0; mt < 2; ++mt)
            #pragma unroll
            for (int reg = 0; reg < 4; ++reg) {
                float e[4], se = 0.f;
                #pragma unroll
                for (int nt = 0; nt < 4; ++nt) {
                    e[nt] = __expf(acc[mt][nt][reg] * facr[mt][reg]);
                    se += e[nt];
                }
                se += __shfl_xor(se, 1, 64);
                se += __shfl_xor(se, 2, 64);
                se += __shfl_xor(se, 4, 64);
                se += __shfl_xor(se, 8, 64);
                float inv = 1.0f / se;
                if (EoS) {   // cache e_vt for the light second pass
                    size_t rbase = ((((size_t)b << 14) + rowbase + mt * 16 + q * 4 + reg) << 6);
                    #pragma unroll
                    for (int nt = 0; nt < 4; ++nt)
                        EoS[rbase + nt * 16 + c16] = e[nt];
                }
                #pragma unroll
                for (int nt = 0; nt < 4; ++nt) {
                    float A = e[nt] * inv;
                    float w = __expf(0.5f * A);
                    zacc[nt] += e[nt]; s1acc[nt] += w; s2acc[nt] += w * A;
                }
            }
        #pragma unroll
        for (int nt = 0; nt < 4; ++nt) {
            zacc[nt]  += __shfl_xor(zacc[nt], 16, 64);  zacc[nt]  += __shfl_xor(zacc[nt], 32, 64);
            s1acc[nt] += __shfl_xor(s1acc[nt], 16, 64); s1acc[nt] += __shfl_xor(s1acc[nt], 32, 64);
            s2acc[nt] += __shfl_xor(s2acc[nt], 16, 64); s2acc[nt] += __shfl_xor(s2acc[nt], 32, 64);
        }
        if (lane < 16) {
            #pragma unroll
            for (int nt = 0; nt < 4; ++nt) {
                zlds[0][wave][nt * 16 + lane] = zacc[nt];
                zlds[1][wave][nt * 16 + lane] = s1acc[nt];
                zlds[2][wave][nt * 16 + lane] = s2acc[nt];
            }
        }
        __syncthreads();
        if (tid < 64) {
            float z  = zlds[0][0][tid] + zlds[0][1][tid] + zlds[0][2][tid] + zlds[0][3][tid];
            float a  = zlds[1][0][tid] + zlds[1][1][tid] + zlds[1][2][tid] + zlds[1][3][tid];
            float s2 = zlds[2][0][tid] + zlds[2][1][tid] + zlds[2][2][tid] + zlds[2][3][tid];
            atomicAdd(&Z[b * LT + tid], z);
            atomicAdd(&S1[b * LT + tid], a);
            atomicAdd(&S2[b * LT + tid], s2);
        }
    } else {
        float cc[4];
        #pragma unroll
        for (int nt = 0; nt < 4; ++nt) cc[nt] = c[b * LT + nt * 16 + c16];
        float lmn = 3.4e38f, lmx = -3.4e38f;
        #pragma unroll
        for (int mt = 0; mt < 2; ++mt)
            #pragma unroll
            for (int reg = 0; reg < 4; ++reg) {
                float x = 0.f;
                #pragma unroll
                for (int nt = 0; nt < 4; ++nt)
                    x += __expf(acc[mt][nt][reg] * facr[mt][reg]) * cc[nt];
                x += __shfl_xor(x, 1, 64);
                x += __shfl_xor(x, 2, 64);
                x += __shfl_xor(x, 4, 64);
                x += __shfl_xor(x, 8, 64);
                if (c16 == 0)
                    EoS[(size_t)b * LV + rowbase + mt * 16 + q * 4 + reg] = x;
                lmn = fminf(lmn, x); lmx = fmaxf(lmx, x);  // dup lanes ok for min/max
            }
        float* rmn = (float*)ldsT;         // ldsT dead now; reuse
        float* rmx = ((float*)ldsT) + 256;
        rmn[tid] = lmn; rmx[tid] = lmx;
        __syncthreads();
        for (int s = 128; s > 0; s >>= 1) {
            if (tid < s) {
                rmn[tid] = fminf(rmn[tid], rmn[tid + s]);
                rmx[tid] = fmaxf(rmx[tid], rmx[tid + s]);
            }
            __syncthreads();
        }
        if (tid == 0) {
            atomicMin(&mnmxU[b * 2],     asu(rmn[0]));
            atomicMax(&mnmxU[b * 2 + 1], asu(rmx[0]));
        }
    }
}

// c[t] = (S2/S1) / ((sum_t S2/S1 + eps) * Z[t])   (fallback path)
__global__ __launch_bounds__(64) void k3_coef(const float* Z, const float* S1,
                                              const float* S2, float* c) {
    int b = blockIdx.x, lane = threadIdx.x;
    float ts = S2[b * LT + lane] / S1[b * LT + lane];
    float tot = ts;
    #pragma unroll
    for (int o = 1; o < 64; o <<= 1) tot += __shfl_xor(tot, o, 64);
    c[b * LT + lane] = ts / ((tot + EPSV) * Z[b * LT + lane]);
}

// Light pass 2: scores[row] = sum_t E[row][t]*c[t], replicating mode-1's exact
// summation order (sequential nt FMA chain + balanced binary tree over c16).
// Fused: per-block inline coef (wave 0 == k3_coef body) + min/max uint atomics.
__global__ __launch_bounds__(256) void k2_scores(const float* E, const float* Zg,
                                                 float* scores, unsigned* mnmxU) {
    __shared__ float cl[64];
    __shared__ float rmn[256], rmx[256];
    int tid = threadIdx.x;
    int b = blockIdx.x >> 6;                 // 64 blocks per batch (16384/256)
    if (tid < 64) {                          // folded k3_coef (bit-identical)
        const float* Z = Zg; const float* S1 = Zg + 512; const float* S2 = Zg + 1024;
        float ts = S2[b * LT + tid] / S1[b * LT + tid];
        float tot = ts;
        #pragma unroll
        for (int o = 1; o < 64; o <<= 1) tot += __shfl_xor(tot, o, 64);
        cl[tid] = ts / ((tot + EPSV) * Z[b * LT + tid]);
    }
    __syncthreads();
    size_t row = (size_t)blockIdx.x * 256 + tid;
    const float* er = E + (row << 6);
    float f[64];
    #pragma unroll
    for (int j = 0; j < 16; ++j) {
        float4 v4 = *(const float4*)(er + j * 4);
        f[j*4+0] = v4.x; f[j*4+1] = v4.y; f[j*4+2] = v4.z; f[j*4+3] = v4.w;
    }
    float p[16];
    #pragma unroll
    for (int i = 0; i < 16; ++i) {
        float x = 0.f;
        #pragma unroll
        for (int nt = 0; nt < 4; ++nt) x += f[nt * 16 + i] * cl[nt * 16 + i];
        p[i] = x;
    }
    // balanced tree == shfl_xor(1,2,4,8) butterfly grouping
    float q1[8], q2[4], q3[2];
    #pragma unroll
    for (int j = 0; j < 8; ++j) q1[j] = p[2*j] + p[2*j+1];
    #pragma unroll
    for (int j = 0; j < 4; ++j) q2[j] = q1[2*j] + q1[2*j+1];
    #pragma unroll
    for (int j = 0; j < 2; ++j) q3[j] = q2[2*j] + q2[2*j+1];
    float x = q3[0] + q3[1];
    scores[row] = x;

    rmn[tid] = x; rmx[tid] = x;
    __syncthreads();
    for (int s = 128; s > 0; s >>= 1) {
        if (tid < s) {
            rmn[tid] = fminf(rmn[tid], rmn[tid + s]);
            rmx[tid] = fmaxf(rmx[tid], rmx[tid + s]);
        }
        __syncthreads();
    }
    if (tid == 0) {
        atomicMin(&mnmxU[b * 2],     asu(rmn[0]));
        atomicMax(&mnmxU[b * 2 + 1], asu(rmx[0]));
    }
}

// Output: normalize scores by per-batch min/max; inline sniff for out dtype.
__global__ __launch_bounds__(256) void k5_out(const float* scores, const float* mnmx,
                                              void* out, const void* v) {
    __shared__ int sflag;
    int tid = threadIdx.x;
    if (tid < 64) { int f = sniff_wave((const u16t*)v, tid); if (tid == 0) sflag = f; }
    __syncthreads();
    int isf32 = sflag;
    int i = blockIdx.x * 256 + tid;
    if (i >= NB * LV) return;
    int b = i >> 14;
    float mn = mnmx[b * 2], mx = mnmx[b * 2 + 1];
    float val = (scores[i] - mn) / (mx - mn + EPSV);
    if (isf32) ((float*)out)[i] = val;
    else ((u16t*)out)[i] = f2bf(val);
}

extern "C" void kernel_launch(void* const* d_in, const int* in_sizes, int n_in,
                              void* d_out, int out_size, void* d_ws, size_t ws_size,
                              hipStream_t stream) {
    const void* t = d_in[0];   // [8,64,256]
    const void* v = d_in[1];   // [8,16384,256]
    char* w = (char*)d_ws;

    const size_t E_BYTES = (size_t)NB * LV * LT * 4;   // 33,554,432
    const size_t NEED_NEW = E_BYTES + 262144 + 524288 + 2080 * 4;

    if (ws_size >= NEED_NEW) {
        // Main path: 4 dispatches.
        float* E      = (float*)w;
        u16t*  tnB    = (u16t*)(w + E_BYTES);
        float* scores = (float*)(w + E_BYTES + 262144);
        float* Z      = (float*)(w + E_BYTES + 262144 + 524288);
        float* S1     = Z + 512;
        float* S2     = Z + 1024;
        unsigned* mnmxU = (unsigned*)(Z + 2048);

        k1_tnorm<<<512, 256, 0, stream>>>(t, v, tnB, Z);
        k_gemmT<0><<<dim3(128, NB), 256, 0, stream>>>(v, tnB, Z, S1, S2, E,
                                                      nullptr, nullptr);
        k2_scores<<<512, 256, 0, stream>>>(E, Z, scores, mnmxU);
        k5_out<<<512, 256, 0, stream>>>(scores, (const float*)mnmxU, d_out, v);
    } else {
        // Small-workspace fallback: two-pass GEMM (no E), correct and self-contained.
        u16t*  tnB    = (u16t*)w;                 // 262144 B
        float* scores = (float*)(w + 262144);     // 524288 B
        float* Z      = (float*)(w + 786432);
        float* S1     = Z + 512;
        float* S2     = Z + 1024;
        float* c      = Z + 1536;
        unsigned* mnmxU = (unsigned*)(Z + 2048);

        k1_tnorm<<<512, 256, 0, stream>>>(t, v, tnB, Z);
        k_gemmT<0><<<dim3(128, NB), 256, 0, stream>>>(v, tnB, Z, S1, S2, nullptr,
                                                      nullptr, nullptr);
        k3_coef<<<NB, 64, 0, stream>>>(Z, S1, S2, c);
        k_gemmT<1><<<dim3(128, NB), 256, 0, stream>>>(v, tnB, Z, S1, S2, scores,
                                                      c, mnmxU);
        k5_out<<<512, 256, 0, stream>>>(scores, (const float*)mnmxU, d_out, v);
    }
}